// Round 2
// baseline (47.253 us; speedup 1.0000x reference)
//
#include <hip/hip_runtime.h>
#include <math.h>

#define D 512
#define NROWS 4096
#define BATCH 16
#define CHUNKS 64           // chunks per batch
#define ROWS_PER_CHUNK 64   // NROWS / CHUNKS
#define MAIN_THREADS 256    // 4 waves
#define WAVES 4
#define ROWS_PER_WAVE 16    // ROWS_PER_CHUNK / WAVES

#define UGROUPS 32
#define UROWS 16            // rows of W per u-partial group

// workspace layout (in floats)
#define WS_PART 0            // UGROUPS*D = 16384
#define WS_U    16384        // 512
#define WS_C    16896        // 1 (padded)
#define WS_RECS 17408        // CHUNKS*BATCH recs * 514 floats
#define REC_STRIDE 514       // {m, l, p[512]}

typedef float f32x4 __attribute__((ext_vector_type(4)));

// ---------- u = W^T v (partials, deterministic) ----------
__global__ void k_u_part(const float* __restrict__ W, const float* __restrict__ v,
                         float* __restrict__ part) {
  int g = blockIdx.x;   // UGROUPS blocks, each UROWS rows of W
  int t = threadIdx.x;  // 256 threads
  float a0 = 0.f, a1 = 0.f;
#pragma unroll
  for (int i = 0; i < UROWS; ++i) {
    int e = g * UROWS + i;
    float ve = v[e];
    a0 = fmaf(ve, W[e * D + t], a0);
    a1 = fmaf(ve, W[e * D + t + 256], a1);
  }
  part[g * D + t] = a0;
  part[g * D + t + 256] = a1;
}

// ---------- finalize u, compute c = b . v ----------
__global__ void k_u_fin(const float* __restrict__ part, const float* __restrict__ bvec,
                        const float* __restrict__ v, float* __restrict__ u,
                        float* __restrict__ cout) {
  int t = threadIdx.x;  // 512
  float s = 0.f;
#pragma unroll
  for (int g = 0; g < UGROUPS; ++g) s += part[g * D + t];
  u[t] = s;
  __shared__ float red[512];
  red[t] = bvec[t] * v[t];
  __syncthreads();
  for (int off = 256; off > 0; off >>= 1) {
    if (t < off) red[t] += red[t + off];
    __syncthreads();
  }
  if (t == 0) cout[0] = red[0];
}

// ---------- main: per-chunk online softmax + weighted x accumulation ----------
__global__ __launch_bounds__(MAIN_THREADS) void k_main(
    const float* __restrict__ x, const int* __restrict__ mask,
    const float* __restrict__ u, const float* __restrict__ cptr,
    float* __restrict__ recs) {
  int chunk = blockIdx.x, b = blockIdx.y;
  int t = threadIdx.x;
  int lane = t & 63, w = t >> 6;

  const f32x4* u4 = (const f32x4*)u;
  f32x4 ua = u4[lane];        // d = 4*lane .. 4*lane+3
  f32x4 ub = u4[64 + lane];   // d = 256+4*lane ..
  float c = cptr[0];

  // wave owns 16 contiguous rows
  int base = b * NROWS + chunk * ROWS_PER_CHUNK + w * ROWS_PER_WAVE;

  // hoist all 16 masks into a register bitmask: one coalesced load,
  // then the hot loop has no memory-gated branch
  unsigned bits;
  {
    int mv = (lane < ROWS_PER_WAVE) ? mask[base + lane] : 0;
    unsigned long long bal = __ballot(mv == 1);
    bits = (unsigned)(bal & 0xFFFFu);
  }

  float m = -INFINITY, l = 0.f;
  f32x4 accA = {0.f, 0.f, 0.f, 0.f}, accB = {0.f, 0.f, 0.f, 0.f};

  const f32x4* xb = (const f32x4*)x;
  if (bits) {
    int r0 = __builtin_ctz(bits); bits &= bits - 1;
    const f32x4* xp = xb + (size_t)(base + r0) * (D / 4);
    f32x4 a0 = __builtin_nontemporal_load(xp + lane);
    f32x4 b0 = __builtin_nontemporal_load(xp + 64 + lane);
    while (true) {
      // 2-deep pipeline: issue next row's loads before this row's reduce
      f32x4 a1, b1;
      bool more = (bits != 0);
      if (more) {
        int r1 = __builtin_ctz(bits); bits &= bits - 1;
        const f32x4* xq = xb + (size_t)(base + r1) * (D / 4);
        a1 = __builtin_nontemporal_load(xq + lane);
        b1 = __builtin_nontemporal_load(xq + 64 + lane);
      }
      float s = a0.x * ua.x + a0.y * ua.y + a0.z * ua.z + a0.w * ua.w
              + b0.x * ub.x + b0.y * ub.y + b0.z * ub.z + b0.w * ub.w;
#pragma unroll
      for (int off = 32; off > 0; off >>= 1) s += __shfl_xor(s, off);
      s += c;
      float mn = fmaxf(m, s);
      float sc = __expf(m - mn);   // m==-inf -> 0
      float wg = __expf(s - mn);
      l = l * sc + wg;
      accA = accA * sc + a0 * wg;
      accB = accB * sc + b0 * wg;
      m = mn;
      if (!more) break;
      a0 = a1; b0 = b1;
    }
  }

  __shared__ float s_m[WAVES], s_l[WAVES];
  __shared__ float pbuf[WAVES][D];
  if (lane == 0) { s_m[w] = m; s_l[w] = l; }
  __syncthreads();

  float M = -INFINITY;
#pragma unroll
  for (int i = 0; i < WAVES; ++i) M = fmaxf(M, s_m[i]);
  float fw = (m == -INFINITY) ? 0.f : __expf(m - M);
  f32x4 sa = accA * fw;
  f32x4 sb = accB * fw;
  *(f32x4*)&pbuf[w][4 * lane] = sa;
  *(f32x4*)&pbuf[w][256 + 4 * lane] = sb;
  __syncthreads();

  float ltot = 0.f;
#pragma unroll
  for (int i = 0; i < WAVES; ++i) {
    float mi = s_m[i];
    float fi = (mi == -INFINITY) ? 0.f : __expf(mi - M);
    ltot += fi * s_l[i];
  }

  float* rec = recs + (size_t)(b * CHUNKS + chunk) * REC_STRIDE;
  if (t == 0) { rec[0] = M; rec[1] = ltot; }
  // 256 threads cover 512 columns, 2 each
#pragma unroll
  for (int col = t; col < D; col += MAIN_THREADS) {
    float sum = 0.f;
#pragma unroll
    for (int i = 0; i < WAVES; ++i) sum += pbuf[i][col];
    rec[2 + col] = sum;
  }
}

// ---------- combine chunk partials per batch ----------
__global__ void k_combine(const float* __restrict__ recs, float* __restrict__ out) {
  int b = blockIdx.x;   // 16
  int t = threadIdx.x;  // 512
  __shared__ float sm[CHUNKS], sl[CHUNKS], sf[CHUNKS];
  if (t < CHUNKS) {
    const float* rec = recs + (size_t)(b * CHUNKS + t) * REC_STRIDE;
    sm[t] = rec[0]; sl[t] = rec[1];
  }
  __syncthreads();
  float M = -INFINITY;
#pragma unroll
  for (int i = 0; i < CHUNKS; ++i) M = fmaxf(M, sm[i]);
  if (t < CHUNKS) sf[t] = (sm[t] == -INFINITY) ? 0.f : __expf(sm[t] - M);
  __syncthreads();
  float ltot = 0.f;
#pragma unroll
  for (int i = 0; i < CHUNKS; ++i) ltot += sf[i] * sl[i];
  float o = 0.f;
  for (int i = 0; i < CHUNKS; ++i)
    o += sf[i] * recs[(size_t)(b * CHUNKS + i) * REC_STRIDE + 2 + t];
  out[b * D + t] = o / ltot;
}

extern "C" void kernel_launch(void* const* d_in, const int* in_sizes, int n_in,
                              void* d_out, int out_size, void* d_ws, size_t ws_size,
                              hipStream_t stream) {
  const float* x    = (const float*)d_in[0];
  const int*   mask = (const int*)d_in[1];
  const float* W    = (const float*)d_in[2];
  const float* bvec = (const float*)d_in[3];
  const float* v    = (const float*)d_in[4];
  float* out = (float*)d_out;
  float* ws  = (float*)d_ws;

  float* part = ws + WS_PART;
  float* u    = ws + WS_U;
  float* c    = ws + WS_C;
  float* recs = ws + WS_RECS;

  k_u_part<<<UGROUPS, 256, 0, stream>>>(W, v, part);
  k_u_fin<<<1, 512, 0, stream>>>(part, bvec, v, u, c);
  dim3 g(CHUNKS, BATCH);
  k_main<<<g, MAIN_THREADS, 0, stream>>>(x, mask, u, c, recs);
  k_combine<<<BATCH, 512, 0, stream>>>(recs, out);
}

// Round 3
// 32.082 us; speedup vs baseline: 1.4729x; 1.4729x over previous
//
#include <hip/hip_runtime.h>
#include <math.h>

#define D 512
#define NROWS 4096
#define BATCH 16
#define CHUNKS 64           // chunks per batch
#define ROWS_PER_CHUNK 64   // NROWS / CHUNKS
#define MAIN_THREADS 256    // 4 waves
#define WAVES 4
#define ROWS_PER_WAVE 16    // ROWS_PER_CHUNK / WAVES

// workspace layout (in floats)
#define WS_U    0            // 512
#define WS_C    512          // 1 (padded to 128)
#define WS_RECS 640          // CHUNKS*BATCH recs * REC_STRIDE floats
#define REC_STRIDE 514       // {m, l, p[512]}

typedef float f32x4 __attribute__((ext_vector_type(4)));

// ---------- u[d] = sum_e v[e]*W[e,d] ; c = b.v  (one kernel, deterministic) ----------
__global__ __launch_bounds__(256) void k_u(const float* __restrict__ W,
                                           const float* __restrict__ bvec,
                                           const float* __restrict__ v,
                                           float* __restrict__ u,
                                           float* __restrict__ cout) {
  int j = blockIdx.x;             // 32 blocks, 16 cols each
  int t = threadIdx.x;            // 256
  int col = t & 15, rc = t >> 4;  // 16 row-chunks of 32 rows
  int d = j * 16 + col;
  float s = 0.f;
#pragma unroll 8
  for (int i = 0; i < 32; ++i) {
    int e = rc * 32 + i;
    s = fmaf(v[e], W[e * D + d], s);
  }
  __shared__ float red[16][17];
  red[rc][col] = s;
  __syncthreads();
  if (rc == 0) {
    float tot = 0.f;
#pragma unroll
    for (int i = 0; i < 16; ++i) tot += red[i][col];
    u[d] = tot;
  }
  if (j == 0) {
    // c = b . v (512 elems, 256 threads x2)
    float p = bvec[t] * v[t] + bvec[t + 256] * v[t + 256];
#pragma unroll
    for (int off = 32; off > 0; off >>= 1) p += __shfl_xor(p, off);
    __shared__ float wred[4];
    if ((t & 63) == 0) wred[t >> 6] = p;
    __syncthreads();
    if (t == 0) cout[0] = wred[0] + wred[1] + wred[2] + wred[3];
  }
}

// ---------- main: per-chunk online softmax + weighted x accumulation ----------
__global__ __launch_bounds__(MAIN_THREADS) void k_main(
    const float* __restrict__ x, const int* __restrict__ mask,
    const float* __restrict__ u, const float* __restrict__ cptr,
    float* __restrict__ recs) {
  int chunk = blockIdx.x, b = blockIdx.y;
  int t = threadIdx.x;
  int lane = t & 63, w = t >> 6;

  const f32x4* u4 = (const f32x4*)u;
  f32x4 ua = u4[lane];        // d = 4*lane .. 4*lane+3
  f32x4 ub = u4[64 + lane];   // d = 256+4*lane ..
  float c = cptr[0];

  // wave owns 16 contiguous rows
  int base = b * NROWS + chunk * ROWS_PER_CHUNK + w * ROWS_PER_WAVE;

  // hoist all 16 masks into a register bitmask: one coalesced 64B load,
  // then every branch below resolves from registers (no memory-gated branch)
  unsigned bits;
  {
    int mv = (lane < ROWS_PER_WAVE) ? mask[base + lane] : 0;
    bits = (unsigned)(__ballot(mv == 1) & 0xFFFFull);
  }

  float m = -INFINITY, l = 0.f;
  f32x4 accA = {0.f, 0.f, 0.f, 0.f}, accB = {0.f, 0.f, 0.f, 0.f};

  const f32x4* xp = (const f32x4*)x + (size_t)base * (D / 4);
  // fully unrolled guarded blocks: compiler/TLP hide latency; plain loads so
  // replays hit the Infinity Cache (x = 128 MiB < 256 MiB L3)
#pragma unroll
  for (int r = 0; r < ROWS_PER_WAVE; ++r) {
    if ((bits >> r) & 1u) {
      f32x4 a = xp[r * (D / 4) + lane];
      f32x4 bb = xp[r * (D / 4) + 64 + lane];
      float s = a.x * ua.x + a.y * ua.y + a.z * ua.z + a.w * ua.w
              + bb.x * ub.x + bb.y * ub.y + bb.z * ub.z + bb.w * ub.w;
#pragma unroll
      for (int off = 32; off > 0; off >>= 1) s += __shfl_xor(s, off);
      s += c;
      float mn = fmaxf(m, s);
      float sc = __expf(m - mn);   // m==-inf -> 0
      float wg = __expf(s - mn);
      l = l * sc + wg;
      accA = accA * sc + a * wg;
      accB = accB * sc + bb * wg;
      m = mn;
    }
  }

  __shared__ float s_m[WAVES], s_l[WAVES];
  __shared__ float pbuf[WAVES][D];
  if (lane == 0) { s_m[w] = m; s_l[w] = l; }
  __syncthreads();

  float M = -INFINITY;
#pragma unroll
  for (int i = 0; i < WAVES; ++i) M = fmaxf(M, s_m[i]);
  float fw = (m == -INFINITY) ? 0.f : __expf(m - M);
  f32x4 sa = accA * fw;
  f32x4 sb = accB * fw;
  *(f32x4*)&pbuf[w][4 * lane] = sa;
  *(f32x4*)&pbuf[w][256 + 4 * lane] = sb;
  __syncthreads();

  float ltot = 0.f;
#pragma unroll
  for (int i = 0; i < WAVES; ++i) {
    float mi = s_m[i];
    float fi = (mi == -INFINITY) ? 0.f : __expf(mi - M);
    ltot += fi * s_l[i];
  }

  float* rec = recs + (size_t)(b * CHUNKS + chunk) * REC_STRIDE;
  if (t == 0) { rec[0] = M; rec[1] = ltot; }
  // 256 threads cover 512 columns, 2 each
#pragma unroll
  for (int col = t; col < D; col += MAIN_THREADS) {
    float sum = 0.f;
#pragma unroll
    for (int i = 0; i < WAVES; ++i) sum += pbuf[i][col];
    rec[2 + col] = sum;
  }
}

// ---------- combine chunk partials per batch ----------
__global__ __launch_bounds__(512) void k_combine(const float* __restrict__ recs,
                                                 float* __restrict__ out) {
  int b = blockIdx.x;   // 16
  int t = threadIdx.x;  // 512
  __shared__ float sm[CHUNKS], sl[CHUNKS], sf[CHUNKS];
  if (t < CHUNKS) {
    const float* rec = recs + (size_t)(b * CHUNKS + t) * REC_STRIDE;
    sm[t] = rec[0]; sl[t] = rec[1];
  }
  __syncthreads();
  float M = -INFINITY;
#pragma unroll
  for (int i = 0; i < CHUNKS; ++i) M = fmaxf(M, sm[i]);
  if (t < CHUNKS) sf[t] = (sm[t] == -INFINITY) ? 0.f : __expf(sm[t] - M);
  __syncthreads();
  float ltot = 0.f;
#pragma unroll
  for (int i = 0; i < CHUNKS; ++i) ltot += sf[i] * sl[i];
  float o = 0.f;
  for (int i = 0; i < CHUNKS; ++i)
    o += sf[i] * recs[(size_t)(b * CHUNKS + i) * REC_STRIDE + 2 + t];
  out[b * D + t] = o / ltot;
}

extern "C" void kernel_launch(void* const* d_in, const int* in_sizes, int n_in,
                              void* d_out, int out_size, void* d_ws, size_t ws_size,
                              hipStream_t stream) {
  const float* x    = (const float*)d_in[0];
  const int*   mask = (const int*)d_in[1];
  const float* W    = (const float*)d_in[2];
  const float* bvec = (const float*)d_in[3];
  const float* v    = (const float*)d_in[4];
  float* out = (float*)d_out;
  float* ws  = (float*)d_ws;

  float* u    = ws + WS_U;
  float* c    = ws + WS_C;
  float* recs = ws + WS_RECS;

  k_u<<<32, 256, 0, stream>>>(W, bvec, v, u, c);
  dim3 g(CHUNKS, BATCH);
  k_main<<<g, MAIN_THREADS, 0, stream>>>(x, mask, u, c, recs);
  k_combine<<<BATCH, 512, 0, stream>>>(recs, out);
}